// Round 2
// baseline (364.924 us; speedup 1.0000x reference)
//
#include <hip/hip_runtime.h>
#include <math.h>

#define B_NUM 4
#define S_LEN 2048
#define D_DIM 1024
#define H_NUM 16
#define W_DIM 64

typedef float4 f4;
typedef _Float16 f16;
typedef f16 f16x8 __attribute__((ext_vector_type(8)));
typedef f16 f16x4 __attribute__((ext_vector_type(4)));
typedef float floatx4 __attribute__((ext_vector_type(4)));

#define GLOAD_LDS16(gp, lp)                                                     \
    __builtin_amdgcn_global_load_lds(                                           \
        (const __attribute__((address_space(1))) void*)(gp),                    \
        (__attribute__((address_space(3))) void*)(lp), 16, 0, 0)

// ---------------------------------------------------------------------------
// Fused pre-pass: one launch does all three independent jobs.
//   blocks [0,4)        : per-batch mask compaction (prefix-sum -> fwdmap/cnt)
//   blocks [4,772)      : W fp32 -> W^T f16 (64x64 tiles, 3 matrices)
//   blocks [772,8964)   : x fp32 -> f16 cast
// Masked keys contribute exp(-10000)==0 -> skipping them is exact.
// ---------------------------------------------------------------------------
#define TR_BLOCKS   768          // 16 x 16 x 3
#define CAST_BLOCKS 8192         // B*S*D / 1024

__global__ __launch_bounds__(256) void prep_kernel(
    const int* __restrict__ mask, short* __restrict__ fwdmap,
    int* __restrict__ cnt,
    const float* __restrict__ Wq, const float* __restrict__ Wk,
    const float* __restrict__ Wv, f16* __restrict__ wt16,
    const float* __restrict__ x, f16* __restrict__ x16)
{
    __shared__ __align__(16) char smraw[64 * 68 * 4];
    const int bx  = blockIdx.x;
    const int tid = threadIdx.x;

    if (bx < 4) {
        // ---- mask compaction ----
        int* sc = (int*)smraw;
        const int b  = bx;
        const int t0 = tid * 8;
#pragma unroll
        for (int j = 0; j < 8; ++j) fwdmap[b * S_LEN + t0 + j] = 0;  // pad default
        int kept[8], c = 0;
#pragma unroll
        for (int j = 0; j < 8; ++j) {
            kept[j] = (mask[b * S_LEN + t0 + j] == 0);
            c += kept[j];
        }
        sc[tid] = c;
        __syncthreads();
        for (int off = 1; off < 256; off <<= 1) {
            int add = (tid >= off) ? sc[tid - off] : 0;
            __syncthreads();
            sc[tid] += add;
            __syncthreads();
        }
        int base = sc[tid] - c;
#pragma unroll
        for (int j = 0; j < 8; ++j)
            if (kept[j]) fwdmap[b * S_LEN + (base++)] = (short)(t0 + j);
        if (tid == 255) {
            cnt[b * 4 + 0] = sc[255];
            cnt[b * 4 + 1] = (sc[255] + 63) & ~63;
            cnt[b * 4 + 2] = (sc[255] + 127) & ~127;
            cnt[b * 4 + 3] = (sc[255] + 255) & ~255;
        }
    } else if (bx < 4 + TR_BLOCKS) {
        // ---- W transpose + cast ----
        float (*ts)[68] = (float(*)[68])smraw;
        const int idx = bx - 4;
        const int k0 = (idx & 15) * 64;
        const int n0 = ((idx >> 4) & 15) * 64;
        const int z  = idx >> 8;
        const float* Wsel = (z == 0) ? Wq : (z == 1) ? Wk : Wv;
        f16* outp = wt16 + (size_t)z * D_DIM * D_DIM;

        const int r  = tid >> 4;
        const int c4 = (tid & 15) * 4;
#pragma unroll
        for (int i = 0; i < 4; ++i) {
            f4 t = *(const f4*)&Wsel[(size_t)(k0 + r + i * 16) * D_DIM + n0 + c4];
            *(f4*)&ts[r + i * 16][c4] = t;
        }
        __syncthreads();
#pragma unroll
        for (int i = 0; i < 4; ++i) {
            int id2 = tid + i * 256;
            int nl = id2 >> 4;
            int k4 = (id2 & 15) * 4;
            f16x4 o;
#pragma unroll
            for (int j = 0; j < 4; ++j) o[j] = (f16)ts[k4 + j][nl];
            *(f16x4*)&outp[(size_t)(n0 + nl) * D_DIM + k0 + k4] = o;
        }
    } else {
        // ---- x -> f16 cast ----
        const size_t i = (size_t)(bx - 4 - TR_BLOCKS) * 256 + tid;
        f4 t = *(const f4*)&x[i * 4];
        f16x4 o;
        o[0] = (f16)t.x; o[1] = (f16)t.y; o[2] = (f16)t.z; o[3] = (f16)t.w;
        *(f16x4*)&x16[i * 4] = o;
    }
}

// ---------------------------------------------------------------------------
// QKV GEMM, f16 MFMA, BK=64, XOR-swizzled LDS (kills the 16-way bank
// conflict of the naive 128B-stride layout: row r's 16B k-chunk c lives at
// slot c^(r&7); global_load_lds sources are permuted per-lane, dest stays
// lane-linear). REVERTED to the proven round-0 structure (68.1 us, 506 TF):
// the 256^2 4-phase variant had 2x per-block throughput but its 272-block
// grid at 1 block/CU residency gave a 2-round makespan (measured 71.4 us,
// occupancy 9.4%) -- net loss. 128^2 tile / 4 waves / 32 KiB LDS gives
// multi-block residency and a smooth ~1050-block grid.
// K/V m-tiles run over COMPACTED rows: A staged through fwdmap gather
// (per-lane global addresses), blocks beyond pad128(count) early-exit,
// epilogue writes jc rows directly (no predication).
//   Q -> (B,H,S,W) * 0.125 ; K -> (B,H,jc,W) ; V -> (B,H,W,jc)
// ---------------------------------------------------------------------------
__global__ __launch_bounds__(256) void qkv_mfma_kernel(
    const f16* __restrict__ x16, const f16* __restrict__ wt16,
    const float* __restrict__ bq, const float* __restrict__ bk,
    const float* __restrict__ bv, const short* __restrict__ fwdmap,
    const int* __restrict__ cnt,
    f16* __restrict__ Qo, f16* __restrict__ Ko, f16* __restrict__ Vo)
{
    __shared__ f16 As[128 * 64];
    __shared__ f16 Bs[128 * 64];

    const int tid  = threadIdx.x;
    const int lane = tid & 63;
    const int wid  = tid >> 6;
    const int lx   = lane & 15;
    const int quad = lane >> 4;
    const int wm   = wid >> 1;
    const int wn   = wid & 1;

    const int r0    = blockIdx.y * 128;
    const int nt    = blockIdx.x;
    const int midx  = nt >> 3;
    const int c0    = (nt & 7) * 128;
    const int bB    = r0 >> 11;               // batch (tiles never straddle)
    const int r0loc = r0 & (S_LEN - 1);

    if (midx > 0 && r0loc >= cnt[bB * 4 + 2]) return;   // block-uniform exit

    const f16* Bg = wt16 + (size_t)midx * D_DIM * D_DIM + (size_t)c0 * D_DIM;

    const int srow = lane >> 3;               // 0..7 within 8-row chunk
    const int scw  = ((lane & 7) ^ srow) * 8; // swizzled source k-chunk

    // A-row (global, batch-absolute) for each of this wave's 4 chunks
    int arows[4];
#pragma unroll
    for (int it = 0; it < 4; ++it) {
        int rl = (wid * 4 + it) * 8 + srow;   // 0..127 within tile
        arows[it] = (midx == 0)
            ? (r0 + rl)
            : (bB * S_LEN + (int)fwdmap[bB * S_LEN + r0loc + rl]);
    }

    floatx4 acc[4][4];
#pragma unroll
    for (int a = 0; a < 4; ++a)
#pragma unroll
        for (int b = 0; b < 4; ++b) { acc[a][b][0]=0.f; acc[a][b][1]=0.f; acc[a][b][2]=0.f; acc[a][b][3]=0.f; }

    for (int k0 = 0; k0 < D_DIM; k0 += 64) {
        __syncthreads();
#pragma unroll
        for (int it = 0; it < 4; ++it) {
            int chunk = wid * 4 + it;            // 0..15
            GLOAD_LDS16(&x16[(size_t)arows[it] * D_DIM + k0 + scw], &As[chunk * 512]);
            GLOAD_LDS16(&Bg[(size_t)(chunk * 8 + srow) * D_DIM + k0 + scw], &Bs[chunk * 512]);
        }
        __syncthreads();

#pragma unroll
        for (int kh = 0; kh < 2; ++kh) {
            const int csw = ((kh * 4 + quad) ^ (lx & 7)) * 8;  // de-swizzle
            f16x8 af[4], bf[4];
#pragma unroll
            for (int tm = 0; tm < 4; ++tm)
                af[tm] = *(const f16x8*)&As[(wm * 64 + tm * 16 + lx) * 64 + csw];
#pragma unroll
            for (int tn = 0; tn < 4; ++tn)
                bf[tn] = *(const f16x8*)&Bs[(wn * 64 + tn * 16 + lx) * 64 + csw];
#pragma unroll
            for (int tm = 0; tm < 4; ++tm)
#pragma unroll
                for (int tn = 0; tn < 4; ++tn)
                    acc[tm][tn] = __builtin_amdgcn_mfma_f32_16x16x32_f16(
                        af[tm], bf[tn], acc[tm][tn], 0, 0, 0);
        }
    }

    const float* bp = (midx == 0) ? bq : (midx == 1) ? bk : bv;
    float bias[4];
#pragma unroll
    for (int tn = 0; tn < 4; ++tn)
        bias[tn] = bp[c0 + wn * 64 + tn * 16 + lx];

    if (midx == 0) {
#pragma unroll
        for (int tm = 0; tm < 4; ++tm) {
            int s = r0loc + wm * 64 + tm * 16 + quad * 4;
#pragma unroll
            for (int tn = 0; tn < 4; ++tn) {
                int gc = c0 + wn * 64 + tn * 16 + lx;
                int h = gc >> 6, w = gc & 63;
                size_t base = (((size_t)(bB * H_NUM + h)) * S_LEN + s) * W_DIM + w;
#pragma unroll
                for (int rr = 0; rr < 4; ++rr)
                    Qo[base + (size_t)rr * W_DIM] =
                        (f16)((acc[tm][tn][rr] + bias[tn]) * 0.125f);
            }
        }
    } else if (midx == 1) {
#pragma unroll
        for (int tm = 0; tm < 4; ++tm) {
            int jc = r0loc + wm * 64 + tm * 16 + quad * 4;
#pragma unroll
            for (int tn = 0; tn < 4; ++tn) {
                int gc = c0 + wn * 64 + tn * 16 + lx;
                int h = gc >> 6, w = gc & 63;
                size_t base = (((size_t)(bB * H_NUM + h)) * S_LEN + jc) * W_DIM + w;
#pragma unroll
                for (int rr = 0; rr < 4; ++rr)
                    Ko[base + (size_t)rr * W_DIM] = (f16)(acc[tm][tn][rr] + bias[tn]);
            }
        }
    } else {
#pragma unroll
        for (int tm = 0; tm < 4; ++tm) {
            int jc = r0loc + wm * 64 + tm * 16 + quad * 4;
#pragma unroll
            for (int tn = 0; tn < 4; ++tn) {
                int gc = c0 + wn * 64 + tn * 16 + lx;
                int h = gc >> 6, w = gc & 63;
                f16x4 v;
#pragma unroll
                for (int rr = 0; rr < 4; ++rr) v[rr] = (f16)(acc[tm][tn][rr] + bias[tn]);
                *(f16x4*)&Vo[(((size_t)(bB * H_NUM + h)) * W_DIM + w) * S_LEN + jc] = v;
            }
        }
    }
}

// ---------------------------------------------------------------------------
// Flash attention over COMPACTED keys, S^T formulation, 2 q-tiles per wave.
// LDS staging REMOVED (guide Common-mistake #7 / m169): per (b,h) the
// K+V working set is ~256 KB -> fully L2-resident, and every fragment-load
// pattern below consumes whole cache lines with no amplification
// (K row = exactly one 128B line; V reads 32B/row/load, the 4-n loop covers
// the full 128B line each iteration). Direct global reads drop the 2
// barriers + vmcnt(0) drain per K-tile and free all LDS (better residency).
// ---------------------------------------------------------------------------
__global__ __launch_bounds__(256) void attn_kernel(
    const f16* __restrict__ Q, const f16* __restrict__ Kc,
    const f16* __restrict__ Vct, const int* __restrict__ cnt,
    float* __restrict__ out)
{
    const int tid  = threadIdx.x;
    const int lane = tid & 63;
    const int wid  = tid >> 6;
    const int lx   = lane & 15;
    const int quad = lane >> 4;
    const int qt = blockIdx.x, h = blockIdx.y, bb = blockIdx.z;

    const int count = cnt[bb * 4 + 0];
    const int scp   = cnt[bb * 4 + 1];

    const size_t hoff = ((size_t)(bb * H_NUM + h)) * S_LEN * W_DIM;
    const f16* Qg = Q + hoff + (size_t)qt * 128 * W_DIM;
    const f16* Kg = Kc + hoff;
    const f16* Vg = Vct + hoff;

    f16x8 qb[2][2];
#pragma unroll
    for (int u = 0; u < 2; ++u) {
        int qrow = u * 64 + wid * 16 + lx;
        qb[u][0] = *(const f16x8*)&Qg[(size_t)qrow * W_DIM + quad * 8];
        qb[u][1] = *(const f16x8*)&Qg[(size_t)qrow * W_DIM + 32 + quad * 8];
    }

    floatx4 o[2][4];
    float lsum[2] = {0.f, 0.f};
#pragma unroll
    for (int u = 0; u < 2; ++u)
#pragma unroll
        for (int wb = 0; wb < 4; ++wb) { o[u][wb][0]=0.f; o[u][wb][1]=0.f; o[u][wb][2]=0.f; o[u][wb][3]=0.f; }

    for (int k0 = 0; k0 < scp; k0 += 64) {
        const bool tail = (k0 + 64 > count);

        f16x4 pb[2][4];
#pragma unroll
        for (int n = 0; n < 4; ++n) {
            const int krow = k0 + n * 16 + lx;
            f16x8 ka0 = *(const f16x8*)&Kg[(size_t)krow * W_DIM + quad * 8];
            f16x8 ka1 = *(const f16x8*)&Kg[(size_t)krow * W_DIM + 32 + quad * 8];
            const int kb = k0 + n * 16 + quad * 4;
#pragma unroll
            for (int u = 0; u < 2; ++u) {
                floatx4 s; s[0]=0.f; s[1]=0.f; s[2]=0.f; s[3]=0.f;
                s = __builtin_amdgcn_mfma_f32_16x16x32_f16(ka0, qb[u][0], s, 0, 0, 0);
                s = __builtin_amdgcn_mfma_f32_16x16x32_f16(ka1, qb[u][1], s, 0, 0, 0);
                float p[4], ls = 0.f;
                if (tail) {
#pragma unroll
                    for (int r = 0; r < 4; ++r) {
                        float sv = (kb + r < count) ? s[r] : -1.0e4f;
                        p[r] = __expf(sv); ls += p[r];
                    }
                } else {
#pragma unroll
                    for (int r = 0; r < 4; ++r) { p[r] = __expf(s[r]); ls += p[r]; }
                }
                lsum[u] += ls;
#pragma unroll
                for (int r = 0; r < 4; ++r) pb[u][n][r] = (f16)p[r];
            }
        }

#pragma unroll
        for (int wb = 0; wb < 4; ++wb) {
#pragma unroll
            for (int n = 0; n < 4; ++n) {
                f16x4 va = *(const f16x4*)&Vg[(size_t)(wb * 16 + lx) * S_LEN
                                              + k0 + n * 16 + quad * 4];
#pragma unroll
                for (int u = 0; u < 2; ++u)
                    o[u][wb] = __builtin_amdgcn_mfma_f32_16x16x16f16(va, pb[u][n], o[u][wb], 0, 0, 0);
            }
        }
    }

#pragma unroll
    for (int u = 0; u < 2; ++u) {
        float ls = lsum[u];
        ls += __shfl_xor(ls, 16);
        ls += __shfl_xor(ls, 32);
        const float rl = 1.0f / ls;
        const int q = qt * 128 + u * 64 + wid * 16 + lx;
        const size_t base = ((size_t)bb * S_LEN + q) * D_DIM + h * W_DIM;
#pragma unroll
        for (int wb = 0; wb < 4; ++wb) {
            f4 r;
            r.x = o[u][wb][0] * rl;
            r.y = o[u][wb][1] * rl;
            r.z = o[u][wb][2] * rl;
            r.w = o[u][wb][3] * rl;
            *(f4*)&out[base + wb * 16 + quad * 4] = r;
        }
    }
}

// ---------------------------------------------------------------------------
extern "C" void kernel_launch(void* const* d_in, const int* in_sizes, int n_in,
                              void* d_out, int out_size, void* d_ws, size_t ws_size,
                              hipStream_t stream)
{
    const float* x    = (const float*)d_in[0];
    const float* Wq   = (const float*)d_in[1];
    const float* bq   = (const float*)d_in[2];
    const float* Wk   = (const float*)d_in[3];
    const float* bk   = (const float*)d_in[4];
    const float* Wv   = (const float*)d_in[5];
    const float* bv   = (const float*)d_in[6];
    const int*   mask = (const int*)d_in[7];
    float* out = (float*)d_out;

    const size_t per = (size_t)B_NUM * H_NUM * S_LEN * W_DIM;  // 8,388,608
    f16*   Q      = (f16*)d_ws;
    f16*   Kc     = Q + per;
    f16*   Vct    = Kc + per;
    f16*   x16    = Vct + per;
    f16*   wt16   = x16 + (size_t)(B_NUM * S_LEN) * D_DIM;
    int*   cnt    = (int*)(wt16 + (size_t)3 * D_DIM * D_DIM);
    short* fwdmap = (short*)(cnt + 4 * B_NUM);

    prep_kernel<<<4 + TR_BLOCKS + CAST_BLOCKS, 256, 0, stream>>>(
        mask, fwdmap, cnt, Wq, Wk, Wv, wt16, x, x16);
    qkv_mfma_kernel<<<dim3(24, 64), 256, 0, stream>>>(
        x16, wt16, bq, bk, bv, fwdmap, cnt, Q, Kc, Vct);
    attn_kernel<<<dim3(S_LEN / 128, H_NUM, B_NUM), 256, 0, stream>>>(
        Q, Kc, Vct, cnt, out);
}

// Round 3
// 242.957 us; speedup vs baseline: 1.5020x; 1.5020x over previous
//
#include <hip/hip_runtime.h>
#include <math.h>

#define B_NUM 4
#define S_LEN 2048
#define D_DIM 1024
#define H_NUM 16
#define W_DIM 64

typedef float4 f4;
typedef _Float16 f16;
typedef f16 f16x8 __attribute__((ext_vector_type(8)));
typedef f16 f16x4 __attribute__((ext_vector_type(4)));
typedef float floatx4 __attribute__((ext_vector_type(4)));

#define GLOAD_LDS16(gp, lp)                                                     \
    __builtin_amdgcn_global_load_lds(                                           \
        (const __attribute__((address_space(1))) void*)(gp),                    \
        (__attribute__((address_space(3))) void*)(lp), 16, 0, 0)

// ---------------------------------------------------------------------------
// Fused pre-pass: one launch does all three independent jobs.
//   blocks [0,4)        : per-batch mask compaction (prefix-sum -> fwdmap/cnt)
//   blocks [4,772)      : W fp32 -> W^T f16 (64x64 tiles, 3 matrices)
//   blocks [772,8964)   : x fp32 -> f16 cast
// Masked keys contribute exp(-10000)==0 -> skipping them is exact.
// ---------------------------------------------------------------------------
#define TR_BLOCKS   768          // 16 x 16 x 3
#define CAST_BLOCKS 8192         // B*S*D / 1024

__global__ __launch_bounds__(256) void prep_kernel(
    const int* __restrict__ mask, short* __restrict__ fwdmap,
    int* __restrict__ cnt,
    const float* __restrict__ Wq, const float* __restrict__ Wk,
    const float* __restrict__ Wv, f16* __restrict__ wt16,
    const float* __restrict__ x, f16* __restrict__ x16)
{
    __shared__ __align__(16) char smraw[64 * 68 * 4];
    const int bx  = blockIdx.x;
    const int tid = threadIdx.x;

    if (bx < 4) {
        // ---- mask compaction ----
        int* sc = (int*)smraw;
        const int b  = bx;
        const int t0 = tid * 8;
#pragma unroll
        for (int j = 0; j < 8; ++j) fwdmap[b * S_LEN + t0 + j] = 0;  // pad default
        int kept[8], c = 0;
#pragma unroll
        for (int j = 0; j < 8; ++j) {
            kept[j] = (mask[b * S_LEN + t0 + j] == 0);
            c += kept[j];
        }
        sc[tid] = c;
        __syncthreads();
        for (int off = 1; off < 256; off <<= 1) {
            int add = (tid >= off) ? sc[tid - off] : 0;
            __syncthreads();
            sc[tid] += add;
            __syncthreads();
        }
        int base = sc[tid] - c;
#pragma unroll
        for (int j = 0; j < 8; ++j)
            if (kept[j]) fwdmap[b * S_LEN + (base++)] = (short)(t0 + j);
        if (tid == 255) {
            cnt[b * 4 + 0] = sc[255];
            cnt[b * 4 + 1] = (sc[255] + 63) & ~63;
            cnt[b * 4 + 2] = (sc[255] + 127) & ~127;
            cnt[b * 4 + 3] = (sc[255] + 255) & ~255;
        }
    } else if (bx < 4 + TR_BLOCKS) {
        // ---- W transpose + cast ----
        float (*ts)[68] = (float(*)[68])smraw;
        const int idx = bx - 4;
        const int k0 = (idx & 15) * 64;
        const int n0 = ((idx >> 4) & 15) * 64;
        const int z  = idx >> 8;
        const float* Wsel = (z == 0) ? Wq : (z == 1) ? Wk : Wv;
        f16* outp = wt16 + (size_t)z * D_DIM * D_DIM;

        const int r  = tid >> 4;
        const int c4 = (tid & 15) * 4;
#pragma unroll
        for (int i = 0; i < 4; ++i) {
            f4 t = *(const f4*)&Wsel[(size_t)(k0 + r + i * 16) * D_DIM + n0 + c4];
            *(f4*)&ts[r + i * 16][c4] = t;
        }
        __syncthreads();
#pragma unroll
        for (int i = 0; i < 4; ++i) {
            int id2 = tid + i * 256;
            int nl = id2 >> 4;
            int k4 = (id2 & 15) * 4;
            f16x4 o;
#pragma unroll
            for (int j = 0; j < 4; ++j) o[j] = (f16)ts[k4 + j][nl];
            *(f16x4*)&outp[(size_t)(n0 + nl) * D_DIM + k0 + k4] = o;
        }
    } else {
        // ---- x -> f16 cast ----
        const size_t i = (size_t)(bx - 4 - TR_BLOCKS) * 256 + tid;
        f4 t = *(const f4*)&x[i * 4];
        f16x4 o;
        o[0] = (f16)t.x; o[1] = (f16)t.y; o[2] = (f16)t.z; o[3] = (f16)t.w;
        *(f16x4*)&x16[i * 4] = o;
    }
}

// ---------------------------------------------------------------------------
// QKV GEMM, f16 MFMA, BK=64, XOR-swizzled LDS. Proven round-0 structure
// (68.1 us, 506 TF). Q is additionally pre-scaled by log2(e) so the attn
// kernel can use native exp2 (v_exp_f32) without a per-element multiply.
// K/V m-tiles run over COMPACTED rows via fwdmap gather; blocks beyond
// pad128(count) early-exit.
//   Q -> (B,H,S,W) * 0.125*log2e ; K -> (B,H,jc,W) ; V -> (B,H,W,jc)
// ---------------------------------------------------------------------------
__global__ __launch_bounds__(256) void qkv_mfma_kernel(
    const f16* __restrict__ x16, const f16* __restrict__ wt16,
    const float* __restrict__ bq, const float* __restrict__ bk,
    const float* __restrict__ bv, const short* __restrict__ fwdmap,
    const int* __restrict__ cnt,
    f16* __restrict__ Qo, f16* __restrict__ Ko, f16* __restrict__ Vo)
{
    __shared__ f16 As[128 * 64];
    __shared__ f16 Bs[128 * 64];

    const int tid  = threadIdx.x;
    const int lane = tid & 63;
    const int wid  = tid >> 6;
    const int lx   = lane & 15;
    const int quad = lane >> 4;
    const int wm   = wid >> 1;
    const int wn   = wid & 1;

    const int r0    = blockIdx.y * 128;
    const int nt    = blockIdx.x;
    const int midx  = nt >> 3;
    const int c0    = (nt & 7) * 128;
    const int bB    = r0 >> 11;               // batch (tiles never straddle)
    const int r0loc = r0 & (S_LEN - 1);

    if (midx > 0 && r0loc >= cnt[bB * 4 + 2]) return;   // block-uniform exit

    const f16* Bg = wt16 + (size_t)midx * D_DIM * D_DIM + (size_t)c0 * D_DIM;

    const int srow = lane >> 3;               // 0..7 within 8-row chunk
    const int scw  = ((lane & 7) ^ srow) * 8; // swizzled source k-chunk

    // A-row (global, batch-absolute) for each of this wave's 4 chunks
    int arows[4];
#pragma unroll
    for (int it = 0; it < 4; ++it) {
        int rl = (wid * 4 + it) * 8 + srow;   // 0..127 within tile
        arows[it] = (midx == 0)
            ? (r0 + rl)
            : (bB * S_LEN + (int)fwdmap[bB * S_LEN + r0loc + rl]);
    }

    floatx4 acc[4][4];
#pragma unroll
    for (int a = 0; a < 4; ++a)
#pragma unroll
        for (int b = 0; b < 4; ++b) { acc[a][b][0]=0.f; acc[a][b][1]=0.f; acc[a][b][2]=0.f; acc[a][b][3]=0.f; }

    for (int k0 = 0; k0 < D_DIM; k0 += 64) {
        __syncthreads();
#pragma unroll
        for (int it = 0; it < 4; ++it) {
            int chunk = wid * 4 + it;            // 0..15
            GLOAD_LDS16(&x16[(size_t)arows[it] * D_DIM + k0 + scw], &As[chunk * 512]);
            GLOAD_LDS16(&Bg[(size_t)(chunk * 8 + srow) * D_DIM + k0 + scw], &Bs[chunk * 512]);
        }
        __syncthreads();

#pragma unroll
        for (int kh = 0; kh < 2; ++kh) {
            const int csw = ((kh * 4 + quad) ^ (lx & 7)) * 8;  // de-swizzle
            f16x8 af[4], bf[4];
#pragma unroll
            for (int tm = 0; tm < 4; ++tm)
                af[tm] = *(const f16x8*)&As[(wm * 64 + tm * 16 + lx) * 64 + csw];
#pragma unroll
            for (int tn = 0; tn < 4; ++tn)
                bf[tn] = *(const f16x8*)&Bs[(wn * 64 + tn * 16 + lx) * 64 + csw];
#pragma unroll
            for (int tm = 0; tm < 4; ++tm)
#pragma unroll
                for (int tn = 0; tn < 4; ++tn)
                    acc[tm][tn] = __builtin_amdgcn_mfma_f32_16x16x32_f16(
                        af[tm], bf[tn], acc[tm][tn], 0, 0, 0);
        }
    }

    const float* bp = (midx == 0) ? bq : (midx == 1) ? bk : bv;
    float bias[4];
#pragma unroll
    for (int tn = 0; tn < 4; ++tn)
        bias[tn] = bp[c0 + wn * 64 + tn * 16 + lx];

    if (midx == 0) {
#pragma unroll
        for (int tm = 0; tm < 4; ++tm) {
            int s = r0loc + wm * 64 + tm * 16 + quad * 4;
#pragma unroll
            for (int tn = 0; tn < 4; ++tn) {
                int gc = c0 + wn * 64 + tn * 16 + lx;
                int h = gc >> 6, w = gc & 63;
                size_t base = (((size_t)(bB * H_NUM + h)) * S_LEN + s) * W_DIM + w;
#pragma unroll
                for (int rr = 0; rr < 4; ++rr)
                    Qo[base + (size_t)rr * W_DIM] =
                        (f16)((acc[tm][tn][rr] + bias[tn]) * 0.18033688f);  // 0.125*log2e
            }
        }
    } else if (midx == 1) {
#pragma unroll
        for (int tm = 0; tm < 4; ++tm) {
            int jc = r0loc + wm * 64 + tm * 16 + quad * 4;
#pragma unroll
            for (int tn = 0; tn < 4; ++tn) {
                int gc = c0 + wn * 64 + tn * 16 + lx;
                int h = gc >> 6, w = gc & 63;
                size_t base = (((size_t)(bB * H_NUM + h)) * S_LEN + jc) * W_DIM + w;
#pragma unroll
                for (int rr = 0; rr < 4; ++rr)
                    Ko[base + (size_t)rr * W_DIM] = (f16)(acc[tm][tn][rr] + bias[tn]);
            }
        }
    } else {
#pragma unroll
        for (int tm = 0; tm < 4; ++tm) {
            int jc = r0loc + wm * 64 + tm * 16 + quad * 4;
#pragma unroll
            for (int tn = 0; tn < 4; ++tn) {
                int gc = c0 + wn * 64 + tn * 16 + lx;
                int h = gc >> 6, w = gc & 63;
                f16x4 v;
#pragma unroll
                for (int rr = 0; rr < 4; ++rr) v[rr] = (f16)(acc[tm][tn][rr] + bias[tn]);
                *(f16x4*)&Vo[(((size_t)(bB * H_NUM + h)) * W_DIM + w) * S_LEN + jc] = v;
            }
        }
    }
}

// ---------------------------------------------------------------------------
// Flash attention over COMPACTED keys, S^T formulation, 2 q-tiles per wave.
// LDS staging RESTORED (round-2 direct-global experiment: 59 -> 203 us,
// MfmaUtil 10% -- L2-hit latency on the MFMA critical path; staging batches
// those loads behind one barrier).
// NEW this round:
//  - T14 async-STAGE split (m214v27 +17%): tile t+1's K/V prefetched into
//    REGISTERS during tile t's compute; after the barrier only cheap
//    ds_writes remain. Global-load latency hides under MFMA+exp.
//  - native exp2 (Q pre-scaled by log2e in qkv epilogue): v_exp_f32 is 2^x,
//    so __expf's extra v_mul per element is gone. exp2(-1e4) == 0 keeps the
//    masked-tail exact.
//  - T5 setprio(1) around MFMA clusters (m191: +4-7% on attn).
// ---------------------------------------------------------------------------
#define LSTR 72

__global__ __launch_bounds__(256) void attn_kernel(
    const f16* __restrict__ Q, const f16* __restrict__ Kc,
    const f16* __restrict__ Vct, const int* __restrict__ cnt,
    float* __restrict__ out)
{
    __shared__ f16 Ks[64][LSTR];      // [jc][k]
    __shared__ f16 Vs[64][LSTR];      // [w][jc]

    const int tid  = threadIdx.x;
    const int lane = tid & 63;
    const int wid  = tid >> 6;
    const int lx   = lane & 15;
    const int quad = lane >> 4;
    const int qt = blockIdx.x, h = blockIdx.y, bb = blockIdx.z;

    const int count = cnt[bb * 4 + 0];
    const int scp   = cnt[bb * 4 + 1];

    const size_t hoff = ((size_t)(bb * H_NUM + h)) * S_LEN * W_DIM;
    const f16* Qg = Q + hoff + (size_t)qt * 128 * W_DIM;
    const f16* Kg = Kc + hoff;
    const f16* Vg = Vct + hoff;

    // staging slots: thread covers rows (srow, srow+32) at k-chunk sc8
    const int srow = tid >> 3;
    const int sc8  = (tid & 7) * 8;

    f16x8 qb[2][2];
#pragma unroll
    for (int u = 0; u < 2; ++u) {
        int qrow = u * 64 + wid * 16 + lx;
        qb[u][0] = *(const f16x8*)&Qg[(size_t)qrow * W_DIM + quad * 8];
        qb[u][1] = *(const f16x8*)&Qg[(size_t)qrow * W_DIM + 32 + quad * 8];
    }

    floatx4 o[2][4];
    float lsum[2] = {0.f, 0.f};
#pragma unroll
    for (int u = 0; u < 2; ++u)
#pragma unroll
        for (int wb = 0; wb < 4; ++wb) { o[u][wb][0]=0.f; o[u][wb][1]=0.f; o[u][wb][2]=0.f; o[u][wb][3]=0.f; }

    // prologue: prefetch tile 0 into registers
    f16x8 kreg0 = *(const f16x8*)&Kg[(size_t)srow * W_DIM + sc8];
    f16x8 kreg1 = *(const f16x8*)&Kg[(size_t)(srow + 32) * W_DIM + sc8];
    f16x8 vreg0 = *(const f16x8*)&Vg[(size_t)srow * S_LEN + sc8];
    f16x8 vreg1 = *(const f16x8*)&Vg[(size_t)(srow + 32) * S_LEN + sc8];

    for (int k0 = 0; k0 < scp; k0 += 64) {
        __syncthreads();                       // all waves done reading prev tile
        *(f16x8*)&Ks[srow][sc8]      = kreg0;
        *(f16x8*)&Ks[srow + 32][sc8] = kreg1;
        *(f16x8*)&Vs[srow][sc8]      = vreg0;
        *(f16x8*)&Vs[srow + 32][sc8] = vreg1;
        if (k0 + 64 < scp) {                   // prefetch t+1 (flies under compute)
            kreg0 = *(const f16x8*)&Kg[(size_t)(k0 + 64 + srow) * W_DIM + sc8];
            kreg1 = *(const f16x8*)&Kg[(size_t)(k0 + 96 + srow) * W_DIM + sc8];
            vreg0 = *(const f16x8*)&Vg[(size_t)srow * S_LEN + k0 + 64 + sc8];
            vreg1 = *(const f16x8*)&Vg[(size_t)(srow + 32) * S_LEN + k0 + 64 + sc8];
        }
        __syncthreads();                       // LDS tile ready

        const bool tail = (k0 + 64 > count);

        f16x4 pb[2][4];
#pragma unroll
        for (int n = 0; n < 4; ++n) {
            f16x8 ka0 = *(const f16x8*)&Ks[n * 16 + lx][quad * 8];
            f16x8 ka1 = *(const f16x8*)&Ks[n * 16 + lx][32 + quad * 8];
            const int kb = k0 + n * 16 + quad * 4;
#pragma unroll
            for (int u = 0; u < 2; ++u) {
                floatx4 s; s[0]=0.f; s[1]=0.f; s[2]=0.f; s[3]=0.f;
                __builtin_amdgcn_s_setprio(1);
                s = __builtin_amdgcn_mfma_f32_16x16x32_f16(ka0, qb[u][0], s, 0, 0, 0);
                s = __builtin_amdgcn_mfma_f32_16x16x32_f16(ka1, qb[u][1], s, 0, 0, 0);
                __builtin_amdgcn_s_setprio(0);
                float p[4], ls = 0.f;
                if (tail) {
#pragma unroll
                    for (int r = 0; r < 4; ++r) {
                        float sv = (kb + r < count) ? s[r] : -1.0e4f;
                        p[r] = exp2f(sv); ls += p[r];
                    }
                } else {
#pragma unroll
                    for (int r = 0; r < 4; ++r) { p[r] = exp2f(s[r]); ls += p[r]; }
                }
                lsum[u] += ls;
#pragma unroll
                for (int r = 0; r < 4; ++r) pb[u][n][r] = (f16)p[r];
            }
        }

        __builtin_amdgcn_s_setprio(1);
#pragma unroll
        for (int wb = 0; wb < 4; ++wb) {
#pragma unroll
            for (int n = 0; n < 4; ++n) {
                f16x4 va = *(const f16x4*)&Vs[wb * 16 + lx][n * 16 + quad * 4];
#pragma unroll
                for (int u = 0; u < 2; ++u)
                    o[u][wb] = __builtin_amdgcn_mfma_f32_16x16x16f16(va, pb[u][n], o[u][wb], 0, 0, 0);
            }
        }
        __builtin_amdgcn_s_setprio(0);
    }

#pragma unroll
    for (int u = 0; u < 2; ++u) {
        float ls = lsum[u];
        ls += __shfl_xor(ls, 16);
        ls += __shfl_xor(ls, 32);
        const float rl = 1.0f / ls;
        const int q = qt * 128 + u * 64 + wid * 16 + lx;
        const size_t base = ((size_t)bb * S_LEN + q) * D_DIM + h * W_DIM;
#pragma unroll
        for (int wb = 0; wb < 4; ++wb) {
            f4 r;
            r.x = o[u][wb][0] * rl;
            r.y = o[u][wb][1] * rl;
            r.z = o[u][wb][2] * rl;
            r.w = o[u][wb][3] * rl;
            *(f4*)&out[base + wb * 16 + quad * 4] = r;
        }
    }
}

// ---------------------------------------------------------------------------
extern "C" void kernel_launch(void* const* d_in, const int* in_sizes, int n_in,
                              void* d_out, int out_size, void* d_ws, size_t ws_size,
                              hipStream_t stream)
{
    const float* x    = (const float*)d_in[0];
    const float* Wq   = (const float*)d_in[1];
    const float* bq   = (const float*)d_in[2];
    const float* Wk   = (const float*)d_in[3];
    const float* bk   = (const float*)d_in[4];
    const float* Wv   = (const float*)d_in[5];
    const float* bv   = (const float*)d_in[6];
    const int*   mask = (const int*)d_in[7];
    float* out = (float*)d_out;

    const size_t per = (size_t)B_NUM * H_NUM * S_LEN * W_DIM;  // 8,388,608
    f16*   Q      = (f16*)d_ws;
    f16*   Kc     = Q + per;
    f16*   Vct    = Kc + per;
    f16*   x16    = Vct + per;
    f16*   wt16   = x16 + (size_t)(B_NUM * S_LEN) * D_DIM;
    int*   cnt    = (int*)(wt16 + (size_t)3 * D_DIM * D_DIM);
    short* fwdmap = (short*)(cnt + 4 * B_NUM);

    prep_kernel<<<4 + TR_BLOCKS + CAST_BLOCKS, 256, 0, stream>>>(
        mask, fwdmap, cnt, Wq, Wk, Wv, wt16, x, x16);
    qkv_mfma_kernel<<<dim3(24, 64), 256, 0, stream>>>(
        x16, wt16, bq, bk, bv, fwdmap, cnt, Q, Kc, Vct);
    attn_kernel<<<dim3(S_LEN / 128, H_NUM, B_NUM), 256, 0, stream>>>(
        Q, Kc, Vct, cnt, out);
}

// Round 4
// 237.476 us; speedup vs baseline: 1.5367x; 1.0231x over previous
//
#include <hip/hip_runtime.h>
#include <math.h>

#define B_NUM 4
#define S_LEN 2048
#define D_DIM 1024
#define H_NUM 16
#define W_DIM 64

typedef float4 f4;
typedef _Float16 f16;
typedef f16 f16x8 __attribute__((ext_vector_type(8)));
typedef f16 f16x4 __attribute__((ext_vector_type(4)));
typedef float floatx4 __attribute__((ext_vector_type(4)));

#define GLOAD_LDS16(gp, lp)                                                     \
    __builtin_amdgcn_global_load_lds(                                           \
        (const __attribute__((address_space(1))) void*)(gp),                    \
        (__attribute__((address_space(3))) void*)(lp), 16, 0, 0)

// ---------------------------------------------------------------------------
// Fused pre-pass: one launch does all three independent jobs.
//   blocks [0,4)        : per-batch mask compaction (prefix-sum -> fwdmap/cnt)
//   blocks [4,772)      : W fp32 -> W^T f16 (64x64 tiles, 3 matrices)
//   blocks [772,8964)   : x fp32 -> f16 cast
// Masked keys contribute exp(-10000)==0 -> skipping them is exact.
// ---------------------------------------------------------------------------
#define TR_BLOCKS   768          // 16 x 16 x 3
#define CAST_BLOCKS 8192         // B*S*D / 1024

__global__ __launch_bounds__(256) void prep_kernel(
    const int* __restrict__ mask, short* __restrict__ fwdmap,
    int* __restrict__ cnt,
    const float* __restrict__ Wq, const float* __restrict__ Wk,
    const float* __restrict__ Wv, f16* __restrict__ wt16,
    const float* __restrict__ x, f16* __restrict__ x16)
{
    __shared__ __align__(16) char smraw[64 * 68 * 4];
    const int bx  = blockIdx.x;
    const int tid = threadIdx.x;

    if (bx < 4) {
        // ---- mask compaction ----
        int* sc = (int*)smraw;
        const int b  = bx;
        const int t0 = tid * 8;
#pragma unroll
        for (int j = 0; j < 8; ++j) fwdmap[b * S_LEN + t0 + j] = 0;  // pad default
        int kept[8], c = 0;
#pragma unroll
        for (int j = 0; j < 8; ++j) {
            kept[j] = (mask[b * S_LEN + t0 + j] == 0);
            c += kept[j];
        }
        sc[tid] = c;
        __syncthreads();
        for (int off = 1; off < 256; off <<= 1) {
            int add = (tid >= off) ? sc[tid - off] : 0;
            __syncthreads();
            sc[tid] += add;
            __syncthreads();
        }
        int base = sc[tid] - c;
#pragma unroll
        for (int j = 0; j < 8; ++j)
            if (kept[j]) fwdmap[b * S_LEN + (base++)] = (short)(t0 + j);
        if (tid == 255) {
            cnt[b * 4 + 0] = sc[255];
            cnt[b * 4 + 1] = (sc[255] + 63) & ~63;
            cnt[b * 4 + 2] = (sc[255] + 127) & ~127;
            cnt[b * 4 + 3] = (sc[255] + 255) & ~255;
        }
    } else if (bx < 4 + TR_BLOCKS) {
        // ---- W transpose + cast ----
        float (*ts)[68] = (float(*)[68])smraw;
        const int idx = bx - 4;
        const int k0 = (idx & 15) * 64;
        const int n0 = ((idx >> 4) & 15) * 64;
        const int z  = idx >> 8;
        const float* Wsel = (z == 0) ? Wq : (z == 1) ? Wk : Wv;
        f16* outp = wt16 + (size_t)z * D_DIM * D_DIM;

        const int r  = tid >> 4;
        const int c4 = (tid & 15) * 4;
#pragma unroll
        for (int i = 0; i < 4; ++i) {
            f4 t = *(const f4*)&Wsel[(size_t)(k0 + r + i * 16) * D_DIM + n0 + c4];
            *(f4*)&ts[r + i * 16][c4] = t;
        }
        __syncthreads();
#pragma unroll
        for (int i = 0; i < 4; ++i) {
            int id2 = tid + i * 256;
            int nl = id2 >> 4;
            int k4 = (id2 & 15) * 4;
            f16x4 o;
#pragma unroll
            for (int j = 0; j < 4; ++j) o[j] = (f16)ts[k4 + j][nl];
            *(f16x4*)&outp[(size_t)(n0 + nl) * D_DIM + k0 + k4] = o;
        }
    } else {
        // ---- x -> f16 cast ----
        const size_t i = (size_t)(bx - 4 - TR_BLOCKS) * 256 + tid;
        f4 t = *(const f4*)&x[i * 4];
        f16x4 o;
        o[0] = (f16)t.x; o[1] = (f16)t.y; o[2] = (f16)t.z; o[3] = (f16)t.w;
        *(f16x4*)&x16[i * 4] = o;
    }
}

// ---------------------------------------------------------------------------
// QKV GEMM, f16 MFMA, BK=64, XOR-swizzled LDS. Proven round-0 structure
// (68.1 us, 506 TF). Q is additionally pre-scaled by log2(e) so the attn
// kernel can use native exp2 (v_exp_f32) without a per-element multiply.
// K/V m-tiles run over COMPACTED rows via fwdmap gather; blocks beyond
// pad128(count) early-exit.
//   Q -> (B,H,S,W) * 0.125*log2e ; K -> (B,H,jc,W) ; V -> (B,H,W,jc)
// ---------------------------------------------------------------------------
__global__ __launch_bounds__(256) void qkv_mfma_kernel(
    const f16* __restrict__ x16, const f16* __restrict__ wt16,
    const float* __restrict__ bq, const float* __restrict__ bk,
    const float* __restrict__ bv, const short* __restrict__ fwdmap,
    const int* __restrict__ cnt,
    f16* __restrict__ Qo, f16* __restrict__ Ko, f16* __restrict__ Vo)
{
    __shared__ f16 As[128 * 64];
    __shared__ f16 Bs[128 * 64];

    const int tid  = threadIdx.x;
    const int lane = tid & 63;
    const int wid  = tid >> 6;
    const int lx   = lane & 15;
    const int quad = lane >> 4;
    const int wm   = wid >> 1;
    const int wn   = wid & 1;

    const int r0    = blockIdx.y * 128;
    const int nt    = blockIdx.x;
    const int midx  = nt >> 3;
    const int c0    = (nt & 7) * 128;
    const int bB    = r0 >> 11;               // batch (tiles never straddle)
    const int r0loc = r0 & (S_LEN - 1);

    if (midx > 0 && r0loc >= cnt[bB * 4 + 2]) return;   // block-uniform exit

    const f16* Bg = wt16 + (size_t)midx * D_DIM * D_DIM + (size_t)c0 * D_DIM;

    const int srow = lane >> 3;               // 0..7 within 8-row chunk
    const int scw  = ((lane & 7) ^ srow) * 8; // swizzled source k-chunk

    // A-row (global, batch-absolute) for each of this wave's 4 chunks
    int arows[4];
#pragma unroll
    for (int it = 0; it < 4; ++it) {
        int rl = (wid * 4 + it) * 8 + srow;   // 0..127 within tile
        arows[it] = (midx == 0)
            ? (r0 + rl)
            : (bB * S_LEN + (int)fwdmap[bB * S_LEN + r0loc + rl]);
    }

    floatx4 acc[4][4];
#pragma unroll
    for (int a = 0; a < 4; ++a)
#pragma unroll
        for (int b = 0; b < 4; ++b) { acc[a][b][0]=0.f; acc[a][b][1]=0.f; acc[a][b][2]=0.f; acc[a][b][3]=0.f; }

    for (int k0 = 0; k0 < D_DIM; k0 += 64) {
        __syncthreads();
#pragma unroll
        for (int it = 0; it < 4; ++it) {
            int chunk = wid * 4 + it;            // 0..15
            GLOAD_LDS16(&x16[(size_t)arows[it] * D_DIM + k0 + scw], &As[chunk * 512]);
            GLOAD_LDS16(&Bg[(size_t)(chunk * 8 + srow) * D_DIM + k0 + scw], &Bs[chunk * 512]);
        }
        __syncthreads();

#pragma unroll
        for (int kh = 0; kh < 2; ++kh) {
            const int csw = ((kh * 4 + quad) ^ (lx & 7)) * 8;  // de-swizzle
            f16x8 af[4], bf[4];
#pragma unroll
            for (int tm = 0; tm < 4; ++tm)
                af[tm] = *(const f16x8*)&As[(wm * 64 + tm * 16 + lx) * 64 + csw];
#pragma unroll
            for (int tn = 0; tn < 4; ++tn)
                bf[tn] = *(const f16x8*)&Bs[(wn * 64 + tn * 16 + lx) * 64 + csw];
#pragma unroll
            for (int tm = 0; tm < 4; ++tm)
#pragma unroll
                for (int tn = 0; tn < 4; ++tn)
                    acc[tm][tn] = __builtin_amdgcn_mfma_f32_16x16x32_f16(
                        af[tm], bf[tn], acc[tm][tn], 0, 0, 0);
        }
    }

    const float* bp = (midx == 0) ? bq : (midx == 1) ? bk : bv;
    float bias[4];
#pragma unroll
    for (int tn = 0; tn < 4; ++tn)
        bias[tn] = bp[c0 + wn * 64 + tn * 16 + lx];

    if (midx == 0) {
#pragma unroll
        for (int tm = 0; tm < 4; ++tm) {
            int s = r0loc + wm * 64 + tm * 16 + quad * 4;
#pragma unroll
            for (int tn = 0; tn < 4; ++tn) {
                int gc = c0 + wn * 64 + tn * 16 + lx;
                int h = gc >> 6, w = gc & 63;
                size_t base = (((size_t)(bB * H_NUM + h)) * S_LEN + s) * W_DIM + w;
#pragma unroll
                for (int rr = 0; rr < 4; ++rr)
                    Qo[base + (size_t)rr * W_DIM] =
                        (f16)((acc[tm][tn][rr] + bias[tn]) * 0.18033688f);  // 0.125*log2e
            }
        }
    } else if (midx == 1) {
#pragma unroll
        for (int tm = 0; tm < 4; ++tm) {
            int jc = r0loc + wm * 64 + tm * 16 + quad * 4;
#pragma unroll
            for (int tn = 0; tn < 4; ++tn) {
                int gc = c0 + wn * 64 + tn * 16 + lx;
                int h = gc >> 6, w = gc & 63;
                size_t base = (((size_t)(bB * H_NUM + h)) * S_LEN + jc) * W_DIM + w;
#pragma unroll
                for (int rr = 0; rr < 4; ++rr)
                    Ko[base + (size_t)rr * W_DIM] = (f16)(acc[tm][tn][rr] + bias[tn]);
            }
        }
    } else {
#pragma unroll
        for (int tm = 0; tm < 4; ++tm) {
            int jc = r0loc + wm * 64 + tm * 16 + quad * 4;
#pragma unroll
            for (int tn = 0; tn < 4; ++tn) {
                int gc = c0 + wn * 64 + tn * 16 + lx;
                int h = gc >> 6, w = gc & 63;
                f16x4 v;
#pragma unroll
                for (int rr = 0; rr < 4; ++rr) v[rr] = (f16)(acc[tm][tn][rr] + bias[tn]);
                *(f16x4*)&Vo[(((size_t)(bB * H_NUM + h)) * W_DIM + w) * S_LEN + jc] = v;
            }
        }
    }
}

// ---------------------------------------------------------------------------
// Flash attention over COMPACTED keys, S^T formulation, 2 q-tiles per wave.
// Round-3 post-mortem: __syncthreads drains vmcnt(0) (compiler semantics),
// so the register prefetch was being flushed at the second barrier every
// k-tile -- latency fully exposed (87 us, MfmaUtil 24%). Fix (T4 mechanism):
// raw s_barrier + hand-placed waits. Second barrier is preceded ONLY by
// lgkmcnt(0) (ds_writes visible); the prefetch globals stay in flight
// across it (they target registers -- no cross-wave hazard). The compiler's
// own vmcnt wait for kreg/vreg lands at the NEXT iteration's ds_writes,
// i.e. after a full compute phase of hiding. Also removed the 8
// setprio toggles/k-tile in QK^T (scheduler fences blocked the exp2<->MFMA
// interleave); kept one pair around the pure-MFMA PV cluster (m191).
// ---------------------------------------------------------------------------
#define LSTR 72

__global__ __launch_bounds__(256) void attn_kernel(
    const f16* __restrict__ Q, const f16* __restrict__ Kc,
    const f16* __restrict__ Vct, const int* __restrict__ cnt,
    float* __restrict__ out)
{
    __shared__ f16 Ks[64][LSTR];      // [jc][k]
    __shared__ f16 Vs[64][LSTR];      // [w][jc]

    const int tid  = threadIdx.x;
    const int lane = tid & 63;
    const int wid  = tid >> 6;
    const int lx   = lane & 15;
    const int quad = lane >> 4;
    const int qt = blockIdx.x, h = blockIdx.y, bb = blockIdx.z;

    const int count = cnt[bb * 4 + 0];
    const int scp   = cnt[bb * 4 + 1];

    const size_t hoff = ((size_t)(bb * H_NUM + h)) * S_LEN * W_DIM;
    const f16* Qg = Q + hoff + (size_t)qt * 128 * W_DIM;
    const f16* Kg = Kc + hoff;
    const f16* Vg = Vct + hoff;

    // staging slots: thread covers rows (srow, srow+32) at k-chunk sc8
    const int srow = tid >> 3;
    const int sc8  = (tid & 7) * 8;

    f16x8 qb[2][2];
#pragma unroll
    for (int u = 0; u < 2; ++u) {
        int qrow = u * 64 + wid * 16 + lx;
        qb[u][0] = *(const f16x8*)&Qg[(size_t)qrow * W_DIM + quad * 8];
        qb[u][1] = *(const f16x8*)&Qg[(size_t)qrow * W_DIM + 32 + quad * 8];
    }

    floatx4 o[2][4];
    float lsum[2] = {0.f, 0.f};
#pragma unroll
    for (int u = 0; u < 2; ++u)
#pragma unroll
        for (int wb = 0; wb < 4; ++wb) { o[u][wb][0]=0.f; o[u][wb][1]=0.f; o[u][wb][2]=0.f; o[u][wb][3]=0.f; }

    // prologue: prefetch tile 0 into registers
    f16x8 kreg0 = *(const f16x8*)&Kg[(size_t)srow * W_DIM + sc8];
    f16x8 kreg1 = *(const f16x8*)&Kg[(size_t)(srow + 32) * W_DIM + sc8];
    f16x8 vreg0 = *(const f16x8*)&Vg[(size_t)srow * S_LEN + sc8];
    f16x8 vreg1 = *(const f16x8*)&Vg[(size_t)(srow + 32) * S_LEN + sc8];

    for (int k0 = 0; k0 < scp; k0 += 64) {
        // all waves done READING the previous tile (no memory drain needed:
        // every LDS read's value was consumed before this point).
        __builtin_amdgcn_s_barrier();
        // compiler inserts the vmcnt wait for kreg/vreg here -- after a full
        // compute phase of hiding (T14).
        *(f16x8*)&Ks[srow][sc8]      = kreg0;
        *(f16x8*)&Ks[srow + 32][sc8] = kreg1;
        *(f16x8*)&Vs[srow][sc8]      = vreg0;
        *(f16x8*)&Vs[srow + 32][sc8] = vreg1;
        if (k0 + 64 < scp) {                   // prefetch t+1 (in flight across barrier)
            kreg0 = *(const f16x8*)&Kg[(size_t)(k0 + 64 + srow) * W_DIM + sc8];
            kreg1 = *(const f16x8*)&Kg[(size_t)(k0 + 96 + srow) * W_DIM + sc8];
            vreg0 = *(const f16x8*)&Vg[(size_t)srow * S_LEN + k0 + 64 + sc8];
            vreg1 = *(const f16x8*)&Vg[(size_t)(srow + 32) * S_LEN + k0 + 64 + sc8];
        }
        // ds_writes visible to the workgroup; vmcnt NOT drained.
        asm volatile("s_waitcnt lgkmcnt(0)" ::: "memory");
        __builtin_amdgcn_sched_barrier(0);
        __builtin_amdgcn_s_barrier();

        const bool tail = (k0 + 64 > count);

        f16x4 pb[2][4];
#pragma unroll
        for (int n = 0; n < 4; ++n) {
            f16x8 ka0 = *(const f16x8*)&Ks[n * 16 + lx][quad * 8];
            f16x8 ka1 = *(const f16x8*)&Ks[n * 16 + lx][32 + quad * 8];
            const int kb = k0 + n * 16 + quad * 4;
#pragma unroll
            for (int u = 0; u < 2; ++u) {
                floatx4 s; s[0]=0.f; s[1]=0.f; s[2]=0.f; s[3]=0.f;
                s = __builtin_amdgcn_mfma_f32_16x16x32_f16(ka0, qb[u][0], s, 0, 0, 0);
                s = __builtin_amdgcn_mfma_f32_16x16x32_f16(ka1, qb[u][1], s, 0, 0, 0);
                float p[4], ls = 0.f;
                if (tail) {
#pragma unroll
                    for (int r = 0; r < 4; ++r) {
                        float sv = (kb + r < count) ? s[r] : -1.0e4f;
                        p[r] = exp2f(sv); ls += p[r];
                    }
                } else {
#pragma unroll
                    for (int r = 0; r < 4; ++r) { p[r] = exp2f(s[r]); ls += p[r]; }
                }
                lsum[u] += ls;
#pragma unroll
                for (int r = 0; r < 4; ++r) pb[u][n][r] = (f16)p[r];
            }
        }

        __builtin_amdgcn_s_setprio(1);
#pragma unroll
        for (int wb = 0; wb < 4; ++wb) {
#pragma unroll
            for (int n = 0; n < 4; ++n) {
                f16x4 va = *(const f16x4*)&Vs[wb * 16 + lx][n * 16 + quad * 4];
#pragma unroll
                for (int u = 0; u < 2; ++u)
                    o[u][wb] = __builtin_amdgcn_mfma_f32_16x16x16f16(va, pb[u][n], o[u][wb], 0, 0, 0);
            }
        }
        __builtin_amdgcn_s_setprio(0);
    }

#pragma unroll
    for (int u = 0; u < 2; ++u) {
        float ls = lsum[u];
        ls += __shfl_xor(ls, 16);
        ls += __shfl_xor(ls, 32);
        const float rl = 1.0f / ls;
        const int q = qt * 128 + u * 64 + wid * 16 + lx;
        const size_t base = ((size_t)bb * S_LEN + q) * D_DIM + h * W_DIM;
#pragma unroll
        for (int wb = 0; wb < 4; ++wb) {
            f4 r;
            r.x = o[u][wb][0] * rl;
            r.y = o[u][wb][1] * rl;
            r.z = o[u][wb][2] * rl;
            r.w = o[u][wb][3] * rl;
            *(f4*)&out[base + wb * 16 + quad * 4] = r;
        }
    }
}

// ---------------------------------------------------------------------------
extern "C" void kernel_launch(void* const* d_in, const int* in_sizes, int n_in,
                              void* d_out, int out_size, void* d_ws, size_t ws_size,
                              hipStream_t stream)
{
    const float* x    = (const float*)d_in[0];
    const float* Wq   = (const float*)d_in[1];
    const float* bq   = (const float*)d_in[2];
    const float* Wk   = (const float*)d_in[3];
    const float* bk   = (const float*)d_in[4];
    const float* Wv   = (const float*)d_in[5];
    const float* bv   = (const float*)d_in[6];
    const int*   mask = (const int*)d_in[7];
    float* out = (float*)d_out;

    const size_t per = (size_t)B_NUM * H_NUM * S_LEN * W_DIM;  // 8,388,608
    f16*   Q      = (f16*)d_ws;
    f16*   Kc     = Q + per;
    f16*   Vct    = Kc + per;
    f16*   x16    = Vct + per;
    f16*   wt16   = x16 + (size_t)(B_NUM * S_LEN) * D_DIM;
    int*   cnt    = (int*)(wt16 + (size_t)3 * D_DIM * D_DIM);
    short* fwdmap = (short*)(cnt + 4 * B_NUM);

    prep_kernel<<<4 + TR_BLOCKS + CAST_BLOCKS, 256, 0, stream>>>(
        mask, fwdmap, cnt, Wq, Wk, Wv, wt16, x, x16);
    qkv_mfma_kernel<<<dim3(24, 64), 256, 0, stream>>>(
        x16, wt16, bq, bk, bv, fwdmap, cnt, Q, Kc, Vct);
    attn_kernel<<<dim3(S_LEN / 128, H_NUM, B_NUM), 256, 0, stream>>>(
        Q, Kc, Vct, cnt, out);
}

// Round 5
// 216.528 us; speedup vs baseline: 1.6853x; 1.0967x over previous
//
#include <hip/hip_runtime.h>
#include <math.h>

#define B_NUM 4
#define S_LEN 2048
#define D_DIM 1024
#define H_NUM 16
#define W_DIM 64

typedef float4 f4;
typedef _Float16 f16;
typedef f16 f16x8 __attribute__((ext_vector_type(8)));
typedef f16 f16x4 __attribute__((ext_vector_type(4)));
typedef float floatx4 __attribute__((ext_vector_type(4)));

#define GLOAD_LDS16(gp, lp)                                                     \
    __builtin_amdgcn_global_load_lds(                                           \
        (const __attribute__((address_space(1))) void*)(gp),                    \
        (__attribute__((address_space(3))) void*)(lp), 16, 0, 0)

// ---------------------------------------------------------------------------
// Fused pre-pass: one launch does all three independent jobs.
//   blocks [0,4)        : per-batch mask compaction (prefix-sum -> fwdmap/cnt)
//   blocks [4,772)      : W fp32 -> W^T f16 (64x64 tiles, 3 matrices)
//   blocks [772,8964)   : x fp32 -> f16 cast
// Masked keys contribute exp(-10000)==0 -> skipping them is exact.
// ---------------------------------------------------------------------------
#define TR_BLOCKS   768          // 16 x 16 x 3
#define CAST_BLOCKS 8192         // B*S*D / 1024

__global__ __launch_bounds__(256) void prep_kernel(
    const int* __restrict__ mask, short* __restrict__ fwdmap,
    int* __restrict__ cnt,
    const float* __restrict__ Wq, const float* __restrict__ Wk,
    const float* __restrict__ Wv, f16* __restrict__ wt16,
    const float* __restrict__ x, f16* __restrict__ x16)
{
    __shared__ __align__(16) char smraw[64 * 68 * 4];
    const int bx  = blockIdx.x;
    const int tid = threadIdx.x;

    if (bx < 4) {
        // ---- mask compaction ----
        int* sc = (int*)smraw;
        const int b  = bx;
        const int t0 = tid * 8;
#pragma unroll
        for (int j = 0; j < 8; ++j) fwdmap[b * S_LEN + t0 + j] = 0;  // pad default
        int kept[8], c = 0;
#pragma unroll
        for (int j = 0; j < 8; ++j) {
            kept[j] = (mask[b * S_LEN + t0 + j] == 0);
            c += kept[j];
        }
        sc[tid] = c;
        __syncthreads();
        for (int off = 1; off < 256; off <<= 1) {
            int add = (tid >= off) ? sc[tid - off] : 0;
            __syncthreads();
            sc[tid] += add;
            __syncthreads();
        }
        int base = sc[tid] - c;
#pragma unroll
        for (int j = 0; j < 8; ++j)
            if (kept[j]) fwdmap[b * S_LEN + (base++)] = (short)(t0 + j);
        if (tid == 255) {
            cnt[b * 4 + 0] = sc[255];
            cnt[b * 4 + 1] = (sc[255] + 63) & ~63;
            cnt[b * 4 + 2] = (sc[255] + 127) & ~127;
            cnt[b * 4 + 3] = (sc[255] + 255) & ~255;
        }
    } else if (bx < 4 + TR_BLOCKS) {
        // ---- W transpose + cast ----
        float (*ts)[68] = (float(*)[68])smraw;
        const int idx = bx - 4;
        const int k0 = (idx & 15) * 64;
        const int n0 = ((idx >> 4) & 15) * 64;
        const int z  = idx >> 8;
        const float* Wsel = (z == 0) ? Wq : (z == 1) ? Wk : Wv;
        f16* outp = wt16 + (size_t)z * D_DIM * D_DIM;

        const int r  = tid >> 4;
        const int c4 = (tid & 15) * 4;
#pragma unroll
        for (int i = 0; i < 4; ++i) {
            f4 t = *(const f4*)&Wsel[(size_t)(k0 + r + i * 16) * D_DIM + n0 + c4];
            *(f4*)&ts[r + i * 16][c4] = t;
        }
        __syncthreads();
#pragma unroll
        for (int i = 0; i < 4; ++i) {
            int id2 = tid + i * 256;
            int nl = id2 >> 4;
            int k4 = (id2 & 15) * 4;
            f16x4 o;
#pragma unroll
            for (int j = 0; j < 4; ++j) o[j] = (f16)ts[k4 + j][nl];
            *(f16x4*)&outp[(size_t)(n0 + nl) * D_DIM + k0 + k4] = o;
        }
    } else {
        // ---- x -> f16 cast ----
        const size_t i = (size_t)(bx - 4 - TR_BLOCKS) * 256 + tid;
        f4 t = *(const f4*)&x[i * 4];
        f16x4 o;
        o[0] = (f16)t.x; o[1] = (f16)t.y; o[2] = (f16)t.z; o[3] = (f16)t.w;
        *(f16x4*)&x16[i * 4] = o;
    }
}

// ---------------------------------------------------------------------------
// QKV GEMM, f16 MFMA, BK=64, XOR-swizzled LDS (conflict-free, measured 0).
// THIS ROUND (T3-minimum 2-phase): double-buffered LDS + single barrier per
// K-step. Old loop was {sync; stage; sync+vmcnt0; compute} -- staging
// latency fully exposed. New loop: {stage t+1 into buf^1; compute buf;
// vmcnt(0); s_barrier} -- the 8 global_load_lds of tile t+1 fly UNDER the
// compute of tile t; the asm "memory" clobber before s_barrier is the
// ordering fence (no sched_barrier pinning, per m141). Buffer safety:
// buf[!cur] staged at iter t was last read at t-1, whose ds_reads retired
// (MFMA data dep) before barrier(t-1), which precedes this stage.
// K/V m-tiles run over COMPACTED rows via fwdmap gather; blocks beyond
// pad128(count) early-exit (before any barrier).
//   Q -> (B,H,S,W) * 0.125 ; K -> (B,H,jc,W) ; V -> (B,H,W,jc)
// ---------------------------------------------------------------------------
#define QSTAGE(BUF, K0) do {                                                    \
    _Pragma("unroll") for (int it_ = 0; it_ < 4; ++it_) {                       \
        int chunk_ = wid * 4 + it_;                                             \
        GLOAD_LDS16(&x16[(size_t)arows[it_] * D_DIM + (K0) + scw],              \
                    &As[BUF][chunk_ * 512]);                                    \
        GLOAD_LDS16(&Bg[(size_t)(chunk_ * 8 + srow) * D_DIM + (K0) + scw],      \
                    &Bs[BUF][chunk_ * 512]);                                    \
    } } while (0)

#define QCOMPUTE(BUF) do {                                                      \
    _Pragma("unroll") for (int kh_ = 0; kh_ < 2; ++kh_) {                       \
        const int csw_ = ((kh_ * 4 + quad) ^ (lx & 7)) * 8;                     \
        f16x8 af_[4], bf_[4];                                                   \
        _Pragma("unroll") for (int tm_ = 0; tm_ < 4; ++tm_)                     \
            af_[tm_] = *(const f16x8*)&As[BUF][(wm * 64 + tm_ * 16 + lx) * 64 + csw_]; \
        _Pragma("unroll") for (int tn_ = 0; tn_ < 4; ++tn_)                     \
            bf_[tn_] = *(const f16x8*)&Bs[BUF][(wn * 64 + tn_ * 16 + lx) * 64 + csw_]; \
        _Pragma("unroll") for (int tm_ = 0; tm_ < 4; ++tm_)                     \
        _Pragma("unroll") for (int tn_ = 0; tn_ < 4; ++tn_)                     \
            acc[tm_][tn_] = __builtin_amdgcn_mfma_f32_16x16x32_f16(             \
                af_[tm_], bf_[tn_], acc[tm_][tn_], 0, 0, 0);                    \
    } } while (0)

#define QVM0BAR() do {                                                          \
    asm volatile("s_waitcnt vmcnt(0)" ::: "memory");                            \
    __builtin_amdgcn_s_barrier();                                               \
    } while (0)

__global__ __launch_bounds__(256) void qkv_mfma_kernel(
    const f16* __restrict__ x16, const f16* __restrict__ wt16,
    const float* __restrict__ bq, const float* __restrict__ bk,
    const float* __restrict__ bv, const short* __restrict__ fwdmap,
    const int* __restrict__ cnt,
    f16* __restrict__ Qo, f16* __restrict__ Ko, f16* __restrict__ Vo)
{
    __shared__ f16 As[2][128 * 64];
    __shared__ f16 Bs[2][128 * 64];

    const int tid  = threadIdx.x;
    const int lane = tid & 63;
    const int wid  = tid >> 6;
    const int lx   = lane & 15;
    const int quad = lane >> 4;
    const int wm   = wid >> 1;
    const int wn   = wid & 1;

    const int r0    = blockIdx.y * 128;
    const int nt    = blockIdx.x;
    const int midx  = nt >> 3;
    const int c0    = (nt & 7) * 128;
    const int bB    = r0 >> 11;               // batch (tiles never straddle)
    const int r0loc = r0 & (S_LEN - 1);

    if (midx > 0 && r0loc >= cnt[bB * 4 + 2]) return;   // block-uniform exit

    const f16* Bg = wt16 + (size_t)midx * D_DIM * D_DIM + (size_t)c0 * D_DIM;

    const int srow = lane >> 3;               // 0..7 within 8-row chunk
    const int scw  = ((lane & 7) ^ srow) * 8; // swizzled source k-chunk

    // A-row (global, batch-absolute) for each of this wave's 4 chunks
    int arows[4];
#pragma unroll
    for (int it = 0; it < 4; ++it) {
        int rl = (wid * 4 + it) * 8 + srow;   // 0..127 within tile
        arows[it] = (midx == 0)
            ? (r0 + rl)
            : (bB * S_LEN + (int)fwdmap[bB * S_LEN + r0loc + rl]);
    }

    floatx4 acc[4][4];
#pragma unroll
    for (int a = 0; a < 4; ++a)
#pragma unroll
        for (int b = 0; b < 4; ++b) { acc[a][b][0]=0.f; acc[a][b][1]=0.f; acc[a][b][2]=0.f; acc[a][b][3]=0.f; }

    // prologue: stage tile 0, wait, sync
    QSTAGE(0, 0);
    QVM0BAR();

    // steady state: 14 iterations (tiles 0..13), stage t+1 under compute t
#pragma unroll 2
    for (int t = 0; t < 14; t += 2) {
        QSTAGE(1, (t + 1) * 64);
        QCOMPUTE(0);
        QVM0BAR();
        QSTAGE(0, (t + 2) * 64);
        QCOMPUTE(1);
        QVM0BAR();
    }
    // tiles 14, 15
    QSTAGE(1, 15 * 64);
    QCOMPUTE(0);
    QVM0BAR();
    QCOMPUTE(1);

    const float* bp = (midx == 0) ? bq : (midx == 1) ? bk : bv;
    float bias[4];
#pragma unroll
    for (int tn = 0; tn < 4; ++tn)
        bias[tn] = bp[c0 + wn * 64 + tn * 16 + lx];

    if (midx == 0) {
#pragma unroll
        for (int tm = 0; tm < 4; ++tm) {
            int s = r0loc + wm * 64 + tm * 16 + quad * 4;
#pragma unroll
            for (int tn = 0; tn < 4; ++tn) {
                int gc = c0 + wn * 64 + tn * 16 + lx;
                int h = gc >> 6, w = gc & 63;
                size_t base = (((size_t)(bB * H_NUM + h)) * S_LEN + s) * W_DIM + w;
#pragma unroll
                for (int rr = 0; rr < 4; ++rr)
                    Qo[base + (size_t)rr * W_DIM] =
                        (f16)((acc[tm][tn][rr] + bias[tn]) * 0.125f);
            }
        }
    } else if (midx == 1) {
#pragma unroll
        for (int tm = 0; tm < 4; ++tm) {
            int jc = r0loc + wm * 64 + tm * 16 + quad * 4;
#pragma unroll
            for (int tn = 0; tn < 4; ++tn) {
                int gc = c0 + wn * 64 + tn * 16 + lx;
                int h = gc >> 6, w = gc & 63;
                size_t base = (((size_t)(bB * H_NUM + h)) * S_LEN + jc) * W_DIM + w;
#pragma unroll
                for (int rr = 0; rr < 4; ++rr)
                    Ko[base + (size_t)rr * W_DIM] = (f16)(acc[tm][tn][rr] + bias[tn]);
            }
        }
    } else {
#pragma unroll
        for (int tm = 0; tm < 4; ++tm) {
            int jc = r0loc + wm * 64 + tm * 16 + quad * 4;
#pragma unroll
            for (int tn = 0; tn < 4; ++tn) {
                int gc = c0 + wn * 64 + tn * 16 + lx;
                int h = gc >> 6, w = gc & 63;
                f16x4 v;
#pragma unroll
                for (int rr = 0; rr < 4; ++rr) v[rr] = (f16)(acc[tm][tn][rr] + bias[tn]);
                *(f16x4*)&Vo[(((size_t)(bB * H_NUM + h)) * W_DIM + w) * S_LEN + jc] = v;
            }
        }
    }
}

// ---------------------------------------------------------------------------
// Flash attention over COMPACTED keys, S^T formulation, 2 q-tiles per wave.
// EXACT round-0 revert (~67 us): the round-3/4 bundle (reg-prefetch
// restructure, exp2f, PV setprio) measured 85-87 us -- exp2f's OCML
// denormal path and scheduler pinning are the suspects; all dropped.
// ---------------------------------------------------------------------------
#define LSTR 72

__global__ __launch_bounds__(256) void attn_kernel(
    const f16* __restrict__ Q, const f16* __restrict__ Kc,
    const f16* __restrict__ Vct, const int* __restrict__ cnt,
    float* __restrict__ out)
{
    __shared__ f16 Ks[64][LSTR];      // [jc][k]
    __shared__ f16 Vs[64][LSTR];      // [w][jc]

    const int tid  = threadIdx.x;
    const int lane = tid & 63;
    const int wid  = tid >> 6;
    const int lx   = lane & 15;
    const int quad = lane >> 4;
    const int qt = blockIdx.x, h = blockIdx.y, bb = blockIdx.z;

    const int count = cnt[bb * 4 + 0];
    const int scp   = cnt[bb * 4 + 1];

    const size_t hoff = ((size_t)(bb * H_NUM + h)) * S_LEN * W_DIM;
    const f16* Qg = Q + hoff + (size_t)qt * 128 * W_DIM;
    const f16* Kg = Kc + hoff;
    const f16* Vg = Vct + hoff;

    f16x8 qb[2][2];
#pragma unroll
    for (int u = 0; u < 2; ++u) {
        int qrow = u * 64 + wid * 16 + lx;
        qb[u][0] = *(const f16x8*)&Qg[(size_t)qrow * W_DIM + quad * 8];
        qb[u][1] = *(const f16x8*)&Qg[(size_t)qrow * W_DIM + 32 + quad * 8];
    }

    floatx4 o[2][4];
    float lsum[2] = {0.f, 0.f};
#pragma unroll
    for (int u = 0; u < 2; ++u)
#pragma unroll
        for (int wb = 0; wb < 4; ++wb) { o[u][wb][0]=0.f; o[u][wb][1]=0.f; o[u][wb][2]=0.f; o[u][wb][3]=0.f; }

    for (int k0 = 0; k0 < scp; k0 += 64) {
        __syncthreads();
#pragma unroll
        for (int it = 0; it < 2; ++it) {
            int idx = tid + it * 256;
            int row = idx >> 3, c8 = (idx & 7) * 8;
            *(f16x8*)&Ks[row][c8] = *(const f16x8*)&Kg[(size_t)(k0 + row) * W_DIM + c8];
            *(f16x8*)&Vs[row][c8] = *(const f16x8*)&Vg[(size_t)row * S_LEN + k0 + c8];
        }
        __syncthreads();

        const bool tail = (k0 + 64 > count);

        f16x4 pb[2][4];
#pragma unroll
        for (int n = 0; n < 4; ++n) {
            f16x8 ka0 = *(const f16x8*)&Ks[n * 16 + lx][quad * 8];
            f16x8 ka1 = *(const f16x8*)&Ks[n * 16 + lx][32 + quad * 8];
            const int kb = k0 + n * 16 + quad * 4;
#pragma unroll
            for (int u = 0; u < 2; ++u) {
                floatx4 s; s[0]=0.f; s[1]=0.f; s[2]=0.f; s[3]=0.f;
                s = __builtin_amdgcn_mfma_f32_16x16x32_f16(ka0, qb[u][0], s, 0, 0, 0);
                s = __builtin_amdgcn_mfma_f32_16x16x32_f16(ka1, qb[u][1], s, 0, 0, 0);
                float p[4], ls = 0.f;
                if (tail) {
#pragma unroll
                    for (int r = 0; r < 4; ++r) {
                        float sv = (kb + r < count) ? s[r] : -1.0e4f;
                        p[r] = __expf(sv); ls += p[r];
                    }
                } else {
#pragma unroll
                    for (int r = 0; r < 4; ++r) { p[r] = __expf(s[r]); ls += p[r]; }
                }
                lsum[u] += ls;
#pragma unroll
                for (int r = 0; r < 4; ++r) pb[u][n][r] = (f16)p[r];
            }
        }

#pragma unroll
        for (int wb = 0; wb < 4; ++wb) {
#pragma unroll
            for (int n = 0; n < 4; ++n) {
                f16x4 va = *(const f16x4*)&Vs[wb * 16 + lx][n * 16 + quad * 4];
#pragma unroll
                for (int u = 0; u < 2; ++u)
                    o[u][wb] = __builtin_amdgcn_mfma_f32_16x16x16f16(va, pb[u][n], o[u][wb], 0, 0, 0);
            }
        }
    }

#pragma unroll
    for (int u = 0; u < 2; ++u) {
        float ls = lsum[u];
        ls += __shfl_xor(ls, 16);
        ls += __shfl_xor(ls, 32);
        const float rl = 1.0f / ls;
        const int q = qt * 128 + u * 64 + wid * 16 + lx;
        const size_t base = ((size_t)bb * S_LEN + q) * D_DIM + h * W_DIM;
#pragma unroll
        for (int wb = 0; wb < 4; ++wb) {
            f4 r;
            r.x = o[u][wb][0] * rl;
            r.y = o[u][wb][1] * rl;
            r.z = o[u][wb][2] * rl;
            r.w = o[u][wb][3] * rl;
            *(f4*)&out[base + wb * 16 + quad * 4] = r;
        }
    }
}

// ---------------------------------------------------------------------------
extern "C" void kernel_launch(void* const* d_in, const int* in_sizes, int n_in,
                              void* d_out, int out_size, void* d_ws, size_t ws_size,
                              hipStream_t stream)
{
    const float* x    = (const float*)d_in[0];
    const float* Wq   = (const float*)d_in[1];
    const float* bq   = (const float*)d_in[2];
    const float* Wk   = (const float*)d_in[3];
    const float* bk   = (const float*)d_in[4];
    const float* Wv   = (const float*)d_in[5];
    const float* bv   = (const float*)d_in[6];
    const int*   mask = (const int*)d_in[7];
    float* out = (float*)d_out;

    const size_t per = (size_t)B_NUM * H_NUM * S_LEN * W_DIM;  // 8,388,608
    f16*   Q      = (f16*)d_ws;
    f16*   Kc     = Q + per;
    f16*   Vct    = Kc + per;
    f16*   x16    = Vct + per;
    f16*   wt16   = x16 + (size_t)(B_NUM * S_LEN) * D_DIM;
    int*   cnt    = (int*)(wt16 + (size_t)3 * D_DIM * D_DIM);
    short* fwdmap = (short*)(cnt + 4 * B_NUM);

    prep_kernel<<<4 + TR_BLOCKS + CAST_BLOCKS, 256, 0, stream>>>(
        mask, fwdmap, cnt, Wq, Wk, Wv, wt16, x, x16);
    qkv_mfma_kernel<<<dim3(24, 64), 256, 0, stream>>>(
        x16, wt16, bq, bk, bv, fwdmap, cnt, Q, Kc, Vct);
    attn_kernel<<<dim3(S_LEN / 128, H_NUM, B_NUM), 256, 0, stream>>>(
        Q, Kc, Vct, cnt, out);
}